// Round 1
// 201.190 us; speedup vs baseline: 1.0435x; 1.0435x over previous
//
#include <hip/hip_runtime.h>
#include <math.h>

// out[b] = log( sum_{kk in [0,65536)} w[kk>>8] * W0[kk, x0[b]] * W1[kk, x1[b]] )
//
// v2: pure split-k. Grid = 256 blocks (1/CU), block `split` owns kk in
// [256*split, 256*split+256) — exactly one latent k, so w[split] is
// block-uniform and applied once in f32 at the end (no per-element VALU mul).
// Each block computes the FULL 256x256 c-tile (W read exactly once = 134 MB,
// the HBM floor), then gathers the 1024 needed (x0,x1) cells through a
// 64-row LDS quarter-tile (aliased over the staging LDS) and writes
// G[b][split] (1 MB). finish: one wave per b, coalesced float4 row read,
// shuffle-reduce, log.

#define KCHUNK 256
#define BK     32
#define NITER  (KCHUNK / BK)   // 8
#define LDSS   40              // shorts per c-row: 32 k + 8 pad = 80 B

typedef float  f32x4  __attribute__((ext_vector_type(4)));
typedef short  bf16x8 __attribute__((ext_vector_type(8)));

static __device__ __forceinline__ short f2bf(float f) {
    // RNE fp32 -> bf16 (inputs are positive probabilities; no NaN/Inf)
    unsigned u = __builtin_bit_cast(unsigned, f);
    u += 0x7fffu + ((u >> 16) & 1u);
    return (short)(u >> 16);
}

__global__ __launch_bounds__(512, 2) void gemm_gather_kernel(
    const int* __restrict__ x, const float* __restrict__ W,
    const float* __restrict__ wsum, float* __restrict__ G)
{
    extern __shared__ char smem[];
    short* __restrict__ As = (short*)smem;                      // [256][LDSS]
    short* __restrict__ Bs = (short*)(smem + 256 * LDSS * 2);   // [256][LDSS]
    float* __restrict__ Sg = (float*)smem;                      // [64][256] epilogue alias

    const int  split = blockIdx.x;                 // 0..255 == latent k
    const long kbase = (long)split * KCHUNK;
    const float* __restrict__ Ag = W + kbase * 256;              // W0 chunk
    const float* __restrict__ Bg = W + 16777216 + kbase * 256;   // W1 chunk

    const int t  = threadIdx.x;
    // staging: 64 c-quads x 8 k-rows, r=0..3 -> 4 float4 per operand per thread
    const int cq = (t & 63) * 4;
    const int kq = (t >> 6) * 4;

    const int lane = t & 63;
    const int wv   = t >> 6;             // wave 0..7
    const int wc0  = (wv & 3) * 64;      // 4 wave-tiles along c0
    const int wc1  = (wv >> 2) * 128;    // 2 along c1
    const int ml   = lane & 15;
    const int qd   = lane >> 4;

    f32x4 acc[4][8];
#pragma unroll
    for (int i = 0; i < 4; ++i)
#pragma unroll
        for (int j = 0; j < 8; ++j) acc[i][j] = (f32x4){0.f, 0.f, 0.f, 0.f};

    for (int it = 0; it < NITER; ++it) {
        float4 a4[4], b4[4];
#pragma unroll
        for (int r = 0; r < 4; ++r) {
            a4[r] = *(const float4*)(Ag + (long)(it * BK + kq + r) * 256 + cq);
            b4[r] = *(const float4*)(Bg + (long)(it * BK + kq + r) * 256 + cq);
        }
        __syncthreads();   // previous iteration's fragment reads complete
        const float* af = reinterpret_cast<const float*>(a4);
        const float* bf = reinterpret_cast<const float*>(b4);
#pragma unroll
        for (int j = 0; j < 4; ++j) {
            short4 av, bv;
            av.x = f2bf(af[0 * 4 + j]);
            av.y = f2bf(af[1 * 4 + j]);
            av.z = f2bf(af[2 * 4 + j]);
            av.w = f2bf(af[3 * 4 + j]);
            *(short4*)&As[(cq + j) * LDSS + kq] = av;   // 8 B aligned
            bv.x = f2bf(bf[0 * 4 + j]);
            bv.y = f2bf(bf[1 * 4 + j]);
            bv.z = f2bf(bf[2 * 4 + j]);
            bv.w = f2bf(bf[3 * 4 + j]);
            *(short4*)&Bs[(cq + j) * LDSS + kq] = bv;
        }
        __syncthreads();
        // fragment: lane holds [c = base+(lane&15)][k = (lane>>4)*8 + j]
        bf16x8 afr[4];
#pragma unroll
        for (int mi = 0; mi < 4; ++mi)
            afr[mi] = *(const bf16x8*)&As[(wc0 + mi * 16 + ml) * LDSS + qd * 8];
#pragma unroll
        for (int ni = 0; ni < 8; ++ni) {
            const bf16x8 bfr = *(const bf16x8*)&Bs[(wc1 + ni * 16 + ml) * LDSS + qd * 8];
#pragma unroll
            for (int mi = 0; mi < 4; ++mi)
                acc[mi][ni] = __builtin_amdgcn_mfma_f32_16x16x32_bf16(
                    afr[mi], bfr, acc[mi][ni], 0, 0, 0);
        }
    }

    // Epilogue: gather the 1024 needed cells of this block's 256x256 tile.
    // C/D layout: col = lane&15, row = (lane>>4)*4 + reg (harness-verified).
    // 4 rounds of 64 c0-rows; waves with wc0==q*64 dump into LDS, everyone looks up.
    const int b0 = t, b1 = t + 512;
    const int2 xa = ((const int2*)x)[b0];   // coalesced (x0, x1) pairs
    const int2 xb = ((const int2*)x)[b1];
    float v0 = 0.f, v1 = 0.f;
#pragma unroll
    for (int q = 0; q < 4; ++q) {
        __syncthreads();                    // prior round's reads complete
        if (wc0 == q * 64) {
#pragma unroll
            for (int mi = 0; mi < 4; ++mi)
#pragma unroll
                for (int ni = 0; ni < 8; ++ni)
#pragma unroll
                    for (int r = 0; r < 4; ++r)
                        Sg[(mi * 16 + qd * 4 + r) * 256 + wc1 + ni * 16 + ml] =
                            acc[mi][ni][r];
        }
        __syncthreads();
        if ((xa.x >> 6) == q) v0 = Sg[(xa.x & 63) * 256 + xa.y];
        if ((xb.x >> 6) == q) v1 = Sg[(xb.x & 63) * 256 + xb.y];
    }
    const float w = wsum[split];            // block-uniform, applied once in f32
    G[(long)b0 * 256 + split] = v0 * w;
    G[(long)b1 * 256 + split] = v1 * w;
}

// One wave per b: contiguous 1 KB row of G, float4 loads, shuffle-reduce, log.
__global__ __launch_bounds__(256) void finish_kernel(
    const float* __restrict__ G, float* __restrict__ out)
{
    const int b    = blockIdx.x * 4 + (threadIdx.x >> 6);
    const int lane = threadIdx.x & 63;
    const float4 g = ((const float4*)(G + (long)b * 256))[lane];
    float v = (g.x + g.y) + (g.z + g.w);
#pragma unroll
    for (int off = 32; off > 0; off >>= 1) v += __shfl_down(v, off);
    if (lane == 0) out[b] = logf(v);
}

extern "C" void kernel_launch(void* const* d_in, const int* in_sizes, int n_in,
                              void* d_out, int out_size, void* d_ws, size_t ws_size,
                              hipStream_t stream)
{
    const int*   x    = (const int*)d_in[0];     // [1024,2] int32
    const float* W    = (const float*)d_in[1];   // [2,256,256,256] fp32
    const float* wsum = (const float*)d_in[2];   // [256] fp32
    float* G   = (float*)d_ws;                   // [1024][256] f32 = 1 MB
    float* out = (float*)d_out;                  // [1024] fp32

    gemm_gather_kernel<<<dim3(256), 512, 65536, stream>>>(x, W, wsum, G);
    finish_kernel<<<dim3(256), 256, 0, stream>>>(G, out);
}